// Round 1
// baseline (431.560 us; speedup 1.0000x reference)
//
#include <hip/hip_runtime.h>
#include <hip/hip_cooperative_groups.h>

namespace cg = cooperative_groups;

#define NN 384
#define HH 768
#define HP 772   // padded LDS row: 8 row bases spread across bank quads, 16B aligned
#define L2E 1.4426950408889634f
#define TWO_L2E 2.8853900817779268f
#define INV_SQRT_H 0.03608439182435161f
#define ATT_L2E (INV_SQRT_H * L2E)   // att -> log2 domain in one constant

__device__ __forceinline__ float exp2_hw(float x) { return __builtin_amdgcn_exp2f(x); }
__device__ __forceinline__ float rcp_hw(float x) { return __builtin_amdgcn_rcpf(x); }

// ---------------- workspace layout (floats) ----------------
#define WS_E(ws)      ((ws))
#define WS_ET(ws)     ((ws) + NN * NN)
#define WS_ROWP(ws)   ((ws) + 2 * NN * NN)            // [48][384] partial row sums of E
#define WS_COLP(ws)   ((ws) + 2 * NN * NN + 48 * NN)  // [48][384] partial col sums of E
#define WS_ROWRS(ws)  ((ws) + 2 * NN * NN + 96 * NN)  // [384] 1/rowSum
#define WS_COLRS(ws)  (WS_ROWRS(ws) + NN)
#define WS_HYPERT(ws) (WS_COLRS(ws) + NN)
#define WS_HYPOT(ws)  (WS_HYPERT(ws) + NN)
#define WS_WHYPER(ws) (WS_HYPOT(ws) + NN)
#define WS_WHYPO(ws)  (WS_WHYPER(ws) + NN)
#define WS_HP(ws)     (WS_WHYPO(ws) + NN)
#define WS_HQ(ws)     (WS_HP(ws) + HH)

// ---------------- P1: one 8x8 tile of E = exp(att), plus partial row/col sums ----------------
// Lane-per-output, 4 waves split k 4-ways, tanh(z)=1-2/(e^{2z}+1), y pre-scaled by 2*log2e.
// No softmax max needed: |att| <= 27.72 so exp2(att*L2E) in [9e-13, 1.1e12] (fp32-safe).
__device__ __forceinline__ void phase1_tile(const float* __restrict__ X,
                                            const float* __restrict__ Y,
                                            float* __restrict__ ws,
                                            float* smem, int tt, int tid) {
    float* xs = smem;
    float* ys = smem + 8 * HP;
    float* part = smem + 16 * HP;   // 256 floats
    float* E = WS_E(ws);
    float* ET = WS_ET(ws);
    float* rowP = WS_ROWP(ws);
    float* colP = WS_COLP(ws);

    const int it = tt / 48, jt = tt - it * 48;
    const int i0 = it * 8, j0 = jt * 8;

    const float4* gx = (const float4*)(X + i0 * HH);
    const float4* gy = (const float4*)(Y + j0 * HH);
#pragma unroll
    for (int p = 0; p < 6; p++) {
        int e = tid + p * 256;
        int r = e / 192, c = e - r * 192;
        float4 vx = gx[e];
        float4 vy = gy[e];
        ((float4*)(xs + r * HP))[c] = vx;
        vy.x *= TWO_L2E; vy.y *= TWO_L2E; vy.z *= TWO_L2E; vy.w *= TWO_L2E;
        ((float4*)(ys + r * HP))[c] = vy;
    }
    __syncthreads();

    const int wv = tid >> 6, ln = tid & 63;
    const int i = ln >> 3, j = ln & 7;
    const float4* xr = (const float4*)(xs + i * HP) + wv * 48;
    const float4* yr = (const float4*)(ys + j * HP) + wv * 48;
    float a0 = 0.f, a1 = 0.f, a2 = 0.f, a3 = 0.f;
#pragma unroll 8
    for (int m = 0; m < 48; m++) {
        float4 a = xr[m];
        float4 b = yr[m];
        a0 += rcp_hw(exp2_hw(a.x * b.x) + 1.f);
        a1 += rcp_hw(exp2_hw(a.y * b.y) + 1.f);
        a2 += rcp_hw(exp2_hw(a.z * b.z) + 1.f);
        a3 += rcp_hw(exp2_hw(a.w * b.w) + 1.f);
    }
    part[wv * 64 + ln] = (a0 + a1) + (a2 + a3);
    __syncthreads();
    if (tid < 64) {
        float s = part[tid] + part[64 + tid] + part[128 + tid] + part[192 + tid];
        float ev = exp2_hw((768.f - 2.f * s) * ATT_L2E);   // E = exp(att)
        int ii = tid >> 3, jj = tid & 7;
        E[(i0 + ii) * NN + (j0 + jj)] = ev;
        ET[(j0 + jj) * NN + (i0 + ii)] = ev;
        // row partial (sum over jj within this tile)
        float rs = ev;
        rs += __shfl_xor(rs, 1, 64); rs += __shfl_xor(rs, 2, 64); rs += __shfl_xor(rs, 4, 64);
        if (jj == 0) rowP[jt * NN + i0 + ii] = rs;
        // col partial (sum over ii within this tile)
        float cs = ev;
        cs += __shfl_xor(cs, 8, 64); cs += __shfl_xor(cs, 16, 64); cs += __shfl_xor(cs, 32, 64);
        if (ii == 0) colP[it * NN + j0 + jj] = cs;
    }
}

// ---------------- P2: typicalness vectors; blocks 0..383 cols, 384..767 rows ----------------
__device__ __forceinline__ void phase2_typ(float* __restrict__ ws, float* red, int b, int tid) {
    const float* E = WS_E(ws);
    const float* ET = WS_ET(ws);
    const bool isCol = b < NN;
    const int x = isCol ? b : b - NN;
    const float* P = isCol ? WS_ROWP(ws) : WS_COLP(ws);
    const float* M = isCol ? ET : E;

    float s1 = 0.f, s2 = 0.f;
#pragma unroll 8
    for (int k = 0; k < 48; k++) {
        s1 += P[k * NN + tid];
        if (tid < 128) s2 += P[k * NN + tid + 256];
    }
    float r1 = rcp_hw(s1);
    float acc = M[x * NN + tid] * r1;
    float r2 = 0.f;
    if (tid < 128) {
        r2 = rcp_hw(s2);
        acc += M[x * NN + tid + 256] * r2;
    }
    if (isCol ? (b == 0) : (b == NN)) {   // publish reciprocals once for P3
        float* RS = isCol ? WS_ROWRS(ws) : WS_COLRS(ws);
        RS[tid] = r1;
        if (tid < 128) RS[tid + 256] = r2;
    }
#pragma unroll
    for (int o = 32; o; o >>= 1) acc += __shfl_xor(acc, o, 64);
    if ((tid & 63) == 0) red[tid >> 6] = acc;
    __syncthreads();
    if (tid == 0) {
        float S = (red[0] + red[1]) + (red[2] + red[3]);
        (isCol ? WS_HYPERT(ws) : WS_HYPOT(ws))[x] = S * (1.f / NN);
    }
}

// ---------------- P3: attention weight vectors ----------------
__device__ __forceinline__ void phase3_w(float* __restrict__ ws, float* red, int b, int tid) {
    const float* E = WS_E(ws);
    const float* ET = WS_ET(ws);
    const bool isCol = b < NN;
    const int x = isCol ? b : b - NN;
    const float* M = isCol ? ET : E;
    const float* RS = isCol ? WS_ROWRS(ws) : WS_COLRS(ws);
    const float* T = isCol ? WS_HYPOT(ws) : WS_HYPERT(ws);

    float acc = M[x * NN + tid] * RS[tid] * T[tid];
    if (tid < 128) acc += M[x * NN + tid + 256] * RS[tid + 256] * T[tid + 256];
#pragma unroll
    for (int o = 32; o; o >>= 1) acc += __shfl_xor(acc, o, 64);
    if ((tid & 63) == 0) red[tid >> 6] = acc;
    __syncthreads();
    if (tid == 0) (isCol ? WS_WHYPER(ws) : WS_WHYPO(ws))[x] = (red[0] + red[1]) + (red[2] + red[3]);
}

// ---------------- P4: prototypes (blocks 0..23 active) ----------------
__device__ __forceinline__ void phase4_proto(const float* __restrict__ X,
                                             const float* __restrict__ Y,
                                             float* __restrict__ ws,
                                             float* red, int b, int tid) {
    const bool hyper = b < 12;
    const int bb = hyper ? b : b - 12;
    const int dl = tid & 63, w = tid >> 6;
    const int d = bb * 64 + dl;
    const float* M = hyper ? Y : X;
    const float* wv = hyper ? WS_WHYPER(ws) : WS_WHYPO(ws);
    float s = 0.f;
    for (int j = w * 96; j < w * 96 + 96; j++) s += wv[j] * M[j * HH + d];
    red[w * 64 + dl] = s;
    __syncthreads();
    if (tid < 64) {
        float S = red[tid] + red[64 + tid] + red[128 + tid] + red[192 + tid];
        (hyper ? WS_HP(ws) : WS_HQ(ws))[bb * 64 + tid] = S;
    }
}

// ---------------- P5: feats + classifier (block 0) ----------------
__device__ __forceinline__ void phase5_cls(const float* __restrict__ W,
                                           const float* __restrict__ bias,
                                           float* __restrict__ ws,
                                           float* __restrict__ out, float* red, int tid) {
    const float* hp = WS_HP(ws);
    const float* hq = WS_HQ(ws);
    float acc0 = 0.f, acc1 = 0.f, acc2 = 0.f;
    for (int d = tid; d < 4 * HH; d += 256) {
        int seg = d / HH, r = d - seg * HH;
        float f = (seg == 0) ? hp[r] : (seg == 1) ? hq[r] : (seg == 2) ? (hp[r] - hq[r]) : (hp[r] * hq[r]);
        acc0 += W[d] * f;
        acc1 += W[3072 + d] * f;
        acc2 += W[6144 + d] * f;
    }
#pragma unroll
    for (int o = 32; o; o >>= 1) {
        acc0 += __shfl_xor(acc0, o, 64);
        acc1 += __shfl_xor(acc1, o, 64);
        acc2 += __shfl_xor(acc2, o, 64);
    }
    if ((tid & 63) == 0) {
        red[0 * 4 + (tid >> 6)] = acc0;
        red[1 * 4 + (tid >> 6)] = acc1;
        red[2 * 4 + (tid >> 6)] = acc2;
    }
    __syncthreads();
    if (tid < 3)
        out[tid] = red[tid * 4 + 0] + red[tid * 4 + 1] + red[tid * 4 + 2] + red[tid * 4 + 3] + bias[tid];
}

// ---------------- fused cooperative kernel: 768 blocks x 256 thr, 3 blocks/CU ----------------
__global__ __launch_bounds__(256, 3) void k_fused(const float* __restrict__ X,
                                                  const float* __restrict__ Y,
                                                  const float* __restrict__ W,
                                                  const float* __restrict__ bias,
                                                  float* __restrict__ out,
                                                  float* __restrict__ ws) {
    __shared__ float smem[16 * HP + 256];   // 50432 B -> 3 blocks/CU (160 KiB LDS)
    float* red = smem + 16 * HP;
    const int tid = threadIdx.x;
    const int b = blockIdx.x;
    cg::grid_group grid = cg::this_grid();

    // P1: 2304 tiles, 3 per block
#pragma unroll
    for (int rep = 0; rep < 3; rep++) phase1_tile(X, Y, ws, smem, b + rep * 768, tid);
    grid.sync();

    phase2_typ(ws, red, b, tid);
    grid.sync();

    phase3_w(ws, red, b, tid);
    grid.sync();

    if (b < 24) phase4_proto(X, Y, ws, red, b, tid);
    grid.sync();

    if (b == 0) phase5_cls(W, bias, ws, out, red, tid);
}

// ---------------- fallback: phase-split plain kernels (used only if coop launch is rejected) ----
__global__ __launch_bounds__(256) void kf_att(const float* __restrict__ X,
                                              const float* __restrict__ Y,
                                              float* __restrict__ ws) {
    __shared__ float smem[16 * HP + 256];
    phase1_tile(X, Y, ws, smem, blockIdx.x, threadIdx.x);
}
__global__ __launch_bounds__(256) void kf_typ(float* __restrict__ ws) {
    __shared__ float red[4];
    phase2_typ(ws, red, blockIdx.x, threadIdx.x);
}
__global__ __launch_bounds__(256) void kf_w(float* __restrict__ ws) {
    __shared__ float red[4];
    phase3_w(ws, red, blockIdx.x, threadIdx.x);
}
__global__ __launch_bounds__(256) void kf_proto(const float* __restrict__ X,
                                                const float* __restrict__ Y,
                                                float* __restrict__ ws) {
    __shared__ float red[256];
    phase4_proto(X, Y, ws, red, blockIdx.x, threadIdx.x);
}
__global__ __launch_bounds__(256) void kf_cls(const float* __restrict__ W,
                                              const float* __restrict__ bias,
                                              float* __restrict__ ws,
                                              float* __restrict__ out) {
    __shared__ float red[12];
    phase5_cls(W, bias, ws, out, red, threadIdx.x);
}

extern "C" void kernel_launch(void* const* d_in, const int* in_sizes, int n_in,
                              void* d_out, int out_size, void* d_ws, size_t ws_size,
                              hipStream_t stream) {
    const float* X = (const float*)d_in[0];   // hypo_embeddings [384,768] fp32
    const float* Y = (const float*)d_in[1];   // hyper_embeddings [384,768] fp32
    const float* W = (const float*)d_in[2];   // W_cls [3,3072] fp32
    const float* B = (const float*)d_in[3];   // b_cls [3] fp32
    float* out = (float*)d_out;
    float* ws = (float*)d_ws;

    void* args[] = {(void*)&X, (void*)&Y, (void*)&W, (void*)&B, (void*)&out, (void*)&ws};
    hipError_t err = hipLaunchCooperativeKernel((void*)k_fused, dim3(768), dim3(256),
                                                args, 0, stream);
    if (err != hipSuccess) {
        // cooperative launch rejected: same phases as 5 plain dependent kernels
        kf_att<<<2304, 256, 0, stream>>>(X, Y, ws);
        kf_typ<<<768, 256, 0, stream>>>(ws);
        kf_w<<<768, 256, 0, stream>>>(ws);
        kf_proto<<<24, 256, 0, stream>>>(X, Y, ws);
        kf_cls<<<1, 256, 0, stream>>>(W, B, ws, out);
    }
}

// Round 2
// 111.716 us; speedup vs baseline: 3.8630x; 3.8630x over previous
//
#include <hip/hip_runtime.h>

#define NN 384
#define HH 768
#define HP 772   // padded LDS row: 8 row bases spread across bank quads, 16B aligned
#define L2E 1.4426950408889634f
#define TWO_L2E 2.8853900817779268f
#define INV_SQRT_H 0.03608439182435161f
#define ATT_L2E (INV_SQRT_H * L2E)   // att -> log2 domain in one constant

__device__ __forceinline__ float exp2_hw(float x) { return __builtin_amdgcn_exp2f(x); }
__device__ __forceinline__ float rcp_hw(float x) { return __builtin_amdgcn_rcpf(x); }

// ---------------- workspace layout (floats) ----------------
#define WS_E(ws)      ((ws))
#define WS_ET(ws)     ((ws) + NN * NN)
#define WS_ROWP(ws)   ((ws) + 2 * NN * NN)            // [48][384] partial row sums of E
#define WS_COLP(ws)   ((ws) + 2 * NN * NN + 48 * NN)  // [48][384] partial col sums of E
#define WS_ROWRS(ws)  ((ws) + 2 * NN * NN + 96 * NN)  // [384] 1/rowSum
#define WS_COLRS(ws)  (WS_ROWRS(ws) + NN)
#define WS_HYPERT(ws) (WS_COLRS(ws) + NN)
#define WS_HYPOT(ws)  (WS_HYPERT(ws) + NN)
#define WS_WHYPER(ws) (WS_HYPOT(ws) + NN)
#define WS_WHYPO(ws)  (WS_WHYPER(ws) + NN)

// ---------------- K1: one 8x8 tile of E = exp(att) + tile-partial row/col sums ------------
// Lane-per-output, 4 waves split k 4-ways, tanh(z)=1-2/(e^{2z}+1), y pre-scaled by 2*log2e.
// No softmax max needed: |att| <= 27.72 so exp2(att*L2E) in [9e-13, 1.1e12] (fp32-safe).
// Block 0 also zeroes the 3-float output (consumed by K4's atomics; stream-ordered).
__global__ __launch_bounds__(256) void k_att(const float* __restrict__ X,
                                             const float* __restrict__ Y,
                                             float* __restrict__ ws,
                                             float* __restrict__ out) {
    __shared__ float smem[16 * HP + 256];
    float* xs = smem;
    float* ys = smem + 8 * HP;
    float* part = smem + 16 * HP;
    float* E = WS_E(ws);
    float* ET = WS_ET(ws);
    float* rowP = WS_ROWP(ws);
    float* colP = WS_COLP(ws);

    const int tid = threadIdx.x;
    const int tt = blockIdx.x;
    const int it = tt / 48, jt = tt - it * 48;
    const int i0 = it * 8, j0 = jt * 8;

    if (tt == 0 && tid < 3) out[tid] = 0.f;   // init for K4 atomics (later dispatch)

    const float4* gx = (const float4*)(X + i0 * HH);
    const float4* gy = (const float4*)(Y + j0 * HH);
#pragma unroll
    for (int p = 0; p < 6; p++) {
        int e = tid + p * 256;
        int r = e / 192, c = e - r * 192;
        float4 vx = gx[e];
        float4 vy = gy[e];
        ((float4*)(xs + r * HP))[c] = vx;
        vy.x *= TWO_L2E; vy.y *= TWO_L2E; vy.z *= TWO_L2E; vy.w *= TWO_L2E;
        ((float4*)(ys + r * HP))[c] = vy;
    }
    __syncthreads();

    const int wv = tid >> 6, ln = tid & 63;
    const int i = ln >> 3, j = ln & 7;
    const float4* xr = (const float4*)(xs + i * HP) + wv * 48;
    const float4* yr = (const float4*)(ys + j * HP) + wv * 48;
    float a0 = 0.f, a1 = 0.f, a2 = 0.f, a3 = 0.f;
#pragma unroll 8
    for (int m = 0; m < 48; m++) {
        float4 a = xr[m];
        float4 b = yr[m];
        a0 += rcp_hw(exp2_hw(a.x * b.x) + 1.f);
        a1 += rcp_hw(exp2_hw(a.y * b.y) + 1.f);
        a2 += rcp_hw(exp2_hw(a.z * b.z) + 1.f);
        a3 += rcp_hw(exp2_hw(a.w * b.w) + 1.f);
    }
    part[wv * 64 + ln] = (a0 + a1) + (a2 + a3);
    __syncthreads();
    if (tid < 64) {
        float s = part[tid] + part[64 + tid] + part[128 + tid] + part[192 + tid];
        float ev = exp2_hw((768.f - 2.f * s) * ATT_L2E);   // E = exp(att)
        int ii = tid >> 3, jj = tid & 7;
        E[(i0 + ii) * NN + (j0 + jj)] = ev;
        ET[(j0 + jj) * NN + (i0 + ii)] = ev;
        // row partial (sum over jj within this tile)
        float rs = ev;
        rs += __shfl_xor(rs, 1, 64); rs += __shfl_xor(rs, 2, 64); rs += __shfl_xor(rs, 4, 64);
        if (jj == 0) rowP[jt * NN + i0 + ii] = rs;
        // col partial (sum over ii within this tile)
        float cs = ev;
        cs += __shfl_xor(cs, 8, 64); cs += __shfl_xor(cs, 16, 64); cs += __shfl_xor(cs, 32, 64);
        if (ii == 0) colP[it * NN + j0 + jj] = cs;
    }
}

// ---------------- K2: typicalness vectors; blocks 0..383 cols, 384..767 rows ----------------
// Fully coalesced: partial arrays + one contiguous E/ET row. Blocks 0 and 384 publish
// the reciprocal row/col sums for K3.
__global__ __launch_bounds__(256) void k_typ(float* __restrict__ ws) {
    __shared__ float red[4];
    const int b = blockIdx.x, tid = threadIdx.x;
    const float* E = WS_E(ws);
    const float* ET = WS_ET(ws);
    const bool isCol = b < NN;
    const int x = isCol ? b : b - NN;
    const float* P = isCol ? WS_ROWP(ws) : WS_COLP(ws);
    const float* M = isCol ? ET : E;

    float s1 = 0.f, s2 = 0.f;
#pragma unroll 8
    for (int k = 0; k < 48; k++) {
        s1 += P[k * NN + tid];
        if (tid < 128) s2 += P[k * NN + tid + 256];
    }
    float r1 = rcp_hw(s1);
    float acc = M[x * NN + tid] * r1;
    float r2 = 0.f;
    if (tid < 128) {
        r2 = rcp_hw(s2);
        acc += M[x * NN + tid + 256] * r2;
    }
    if (isCol ? (b == 0) : (b == NN)) {   // publish reciprocals once for K3
        float* RS = isCol ? WS_ROWRS(ws) : WS_COLRS(ws);
        RS[tid] = r1;
        if (tid < 128) RS[tid + 256] = r2;
    }
#pragma unroll
    for (int o = 32; o; o >>= 1) acc += __shfl_xor(acc, o, 64);
    if ((tid & 63) == 0) red[tid >> 6] = acc;
    __syncthreads();
    if (tid == 0) {
        float S = (red[0] + red[1]) + (red[2] + red[3]);
        (isCol ? WS_HYPERT(ws) : WS_HYPOT(ws))[x] = S * (1.f / NN);
    }
}

// ---------------- K3: attention weight vectors ----------------
// w_hyper[j] = sum_i E[i][j]*rowRS[i]*hypo_typ[i] ; w_hypo[i] = sum_j E[i][j]*colRS[j]*hyper_typ[j]
__global__ __launch_bounds__(256) void k_w(float* __restrict__ ws) {
    __shared__ float red[4];
    const int b = blockIdx.x, tid = threadIdx.x;
    const float* E = WS_E(ws);
    const float* ET = WS_ET(ws);
    const bool isCol = b < NN;
    const int x = isCol ? b : b - NN;
    const float* M = isCol ? ET : E;
    const float* RS = isCol ? WS_ROWRS(ws) : WS_COLRS(ws);
    const float* T = isCol ? WS_HYPOT(ws) : WS_HYPERT(ws);

    float acc = M[x * NN + tid] * RS[tid] * T[tid];
    if (tid < 128) acc += M[x * NN + tid + 256] * RS[tid + 256] * T[tid + 256];
#pragma unroll
    for (int o = 32; o; o >>= 1) acc += __shfl_xor(acc, o, 64);
    if ((tid & 63) == 0) red[tid >> 6] = acc;
    __syncthreads();
    if (tid == 0) (isCol ? WS_WHYPER(ws) : WS_WHYPO(ws))[x] = (red[0] + red[1]) + (red[2] + red[3]);
}

// ---------------- K4: prototypes + classifier, fused ----------------
// 12 blocks; block bb owns d in [bb*64, bb*64+64). Computes hp and hq slices (4 waves
// k-split over j), forms all 4 feature segments locally, partial-dots against the 3
// classifier rows, atomicAdds 3 scalars into out (zeroed by K1). Block 0 adds bias.
__global__ __launch_bounds__(256) void k_pc(const float* __restrict__ X,
                                            const float* __restrict__ Y,
                                            const float* __restrict__ W,
                                            const float* __restrict__ bias,
                                            const float* __restrict__ ws,
                                            float* __restrict__ out) {
    __shared__ float red[2][4][64];
    __shared__ float hp_s[64], hq_s[64];
    const int tid = threadIdx.x, bb = blockIdx.x;
    const int dl = tid & 63, w = tid >> 6;
    const int d = bb * 64 + dl;
    const float* w_hyper = WS_WHYPER((float*)ws);
    const float* w_hypo  = WS_WHYPO((float*)ws);

    float sp = 0.f, sq = 0.f;
    for (int j = w * 96; j < w * 96 + 96; j++) {
        sp += w_hyper[j] * Y[j * HH + d];
        sq += w_hypo[j]  * X[j * HH + d];
    }
    red[0][w][dl] = sp;
    red[1][w][dl] = sq;
    __syncthreads();
    if (tid < 64) {
        hp_s[tid] = red[0][0][tid] + red[0][1][tid] + red[0][2][tid] + red[0][3][tid];
        hq_s[tid] = red[1][0][tid] + red[1][1][tid] + red[1][2][tid] + red[1][3][tid];
    }
    __syncthreads();

    // waves 0..2 -> classifier rows 0..2; feats = [hp, hq, hp-hq, hp*hq]
    float acc = 0.f;
    if (tid < 192) {
        const int c = tid >> 6;
        const float hp = hp_s[dl], hq = hq_s[dl];
        const int base = c * 3072 + bb * 64 + dl;
        acc = W[base] * hp + W[base + 768] * hq + W[base + 1536] * (hp - hq)
            + W[base + 2304] * (hp * hq);
    }
#pragma unroll
    for (int o = 32; o; o >>= 1) acc += __shfl_xor(acc, o, 64);
    if (tid < 192 && (tid & 63) == 0) atomicAdd(out + (tid >> 6), acc);
    if (bb == 0 && tid < 3) atomicAdd(out + tid, bias[tid]);
}

extern "C" void kernel_launch(void* const* d_in, const int* in_sizes, int n_in,
                              void* d_out, int out_size, void* d_ws, size_t ws_size,
                              hipStream_t stream) {
    const float* X = (const float*)d_in[0];   // hypo_embeddings [384,768] fp32
    const float* Y = (const float*)d_in[1];   // hyper_embeddings [384,768] fp32
    const float* W = (const float*)d_in[2];   // W_cls [3,3072] fp32
    const float* B = (const float*)d_in[3];   // b_cls [3] fp32
    float* out = (float*)d_out;
    float* ws = (float*)d_ws;

    k_att<<<2304, 256, 0, stream>>>(X, Y, ws, out);
    k_typ<<<768, 256, 0, stream>>>(ws);
    k_w<<<768, 256, 0, stream>>>(ws);
    k_pc<<<12, 256, 0, stream>>>(X, Y, W, B, ws, out);
}